// Round 3
// baseline (229.297 us; speedup 1.0000x reference)
//
#include <hip/hip_runtime.h>
#include <hip/hip_bf16.h>

#define IN_C  128
#define OUT_C 256
#define HIMG  56
#define WIMG  56
#define BIMG  32
#define HW    (HIMG * WIMG)     // 3136
#define KW    1152              // 9 * 128, GEMM K

#define BM    128               // oc per block
#define TH    4                 // output rows per block
#define XROWS 6                 // TH + 2 halo
#define XCOLS 58                // 56 + 2 halo
#define NPIXT (XROWS * XCOLS)   // 348 staged pixels

typedef __attribute__((ext_vector_type(8))) short short8;
typedef __attribute__((ext_vector_type(4))) float float4_;

__device__ __forceinline__ unsigned short f32_to_bf16_rne(float f) {
    unsigned u = __builtin_bit_cast(unsigned, f);
    u += 0x7FFFu + ((u >> 16) & 1u);
    return (unsigned short)(u >> 16);
}

// One-shot repack: Wt[oc][r*128+ic] (bf16 bits) <- Wk[oc][ic*9+r] (fp32)
__global__ void repack_w(const float* __restrict__ Wk, unsigned short* __restrict__ Wt) {
    int idx = blockIdx.x * 256 + threadIdx.x;
    if (idx >= OUT_C * KW) return;
    int oc  = idx / KW;
    int rem = idx - oc * KW;
    int r   = rem >> 7;
    int ic  = rem & 127;
    Wt[idx] = f32_to_bf16_rne(Wk[oc * KW + ic * 9 + r]);
}

// Implicit-GEMM conv. A (weights) fragments load DIRECTLY from L2-resident Wt
// (no LDS round-trip), prefetched one t ahead. Barriers only bracket Xs
// staging (8 per block instead of 72) — waves free-run across the 9 taps.
__global__ __launch_bounds__(256, 2) void conv_gemm(
    const float* __restrict__ x, const unsigned short* __restrict__ Wt,
    const float* __restrict__ bias, float* __restrict__ out)
{
    __shared__ short Xs[NPIXT * 32];      // 22272 B, x slice [pix][32ic] w/ swizzle

    const int tid  = threadIdx.x;
    const int lane = tid & 63;
    const int wid  = tid >> 6;
    const int bx   = blockIdx.x;          // 0..447
    const int b    = bx / 14;
    const int h0   = (bx - b * 14) * TH;
    const int oc0  = blockIdx.y * BM;

    // 4 waves, each owns a 64(m) x 112(n) quadrant: 4x7 MFMA tiles
    const int wm = (wid >> 1) * 64;
    const int wn = (wid & 1) * 112;

    // per-lane geometry for the 7 n-fragments (loop-invariant)
    int lp0[7], outoff[7];
    #pragma unroll
    for (int ni = 0; ni < 7; ++ni) {
        int nl  = wn + ni * 16 + (lane & 15);
        int ht_ = nl / 56;
        int wt_ = nl - ht_ * 56;
        lp0[ni]    = (ht_ + 1) * XCOLS + (wt_ + 1);  // tap (0,0) pixel in Xs
        outoff[ni] = (h0 + ht_) * WIMG + wt_;
    }

    // A-fragment lane base: row = oc0+wm+(lane&15), k-offset (lane>>4)*8.
    // Lanes {l,l+16,l+32,l+48} share one 64B line -> minimal L2 requests.
    const unsigned short* aLane = Wt + (size_t)(oc0 + wm + (lane & 15)) * KW + (lane >> 4) * 8;

    float4_ acc[4][7];
    #pragma unroll
    for (int mi = 0; mi < 4; ++mi)
        #pragma unroll
        for (int ni = 0; ni < 7; ++ni) acc[mi][ni] = (float4_)0.0f;

    const int q = lane >> 4;

    // prefetch A fragments for t=0 (koff = 0)
    short8 anx[4];
    #pragma unroll
    for (int mi = 0; mi < 4; ++mi)
        anx[mi] = *(const short8*)(aLane + (size_t)mi * 16 * KW);

    for (int t = 0; t < 36; ++t) {        // t = icq*9 + r
        const int icq = t / 9;
        const int r   = t - icq * 9;

        if (r == 0) {
            if (t) __syncthreads();       // all waves done reading prev Xs
            // ---- stage Xs: x[b][icq*32..+32][h0-1..h0+4][-1..57] -> bf16 LDS ----
            for (int pix = tid; pix < NPIXT; pix += 256) {
                int row  = pix / XCOLS;
                int colw = pix - row * XCOLS;
                int h = h0 + row - 1;
                int w = colw - 1;
                bool valid = ((unsigned)h < HIMG) & ((unsigned)w < WIMG);
                const int sw = (pix >> 1) & 3;
                #pragma unroll
                for (int qb = 0; qb < 4; ++qb) {
                    const float* src = x + (size_t)(b * IN_C + icq * 32 + qb * 8) * HW
                                         + (ptrdiff_t)(h * WIMG + w);
                    short8 v;
                    #pragma unroll
                    for (int j = 0; j < 8; ++j) {
                        float f = valid ? src[(size_t)j * HW] : 0.0f;
                        v[j] = (short)f32_to_bf16_rne(f);
                    }
                    *(short8*)&Xs[pix * 32 + (qb ^ sw) * 8] = v;
                }
            }
            __syncthreads();
        }

        // consume prefetched A, issue next prefetch
        short8 afr[4];
        #pragma unroll
        for (int mi = 0; mi < 4; ++mi) afr[mi] = anx[mi];
        if (t < 35) {
            const int t1   = t + 1;
            const int icq1 = t1 / 9;
            const int r1   = t1 - icq1 * 9;
            const int koff = r1 * 128 + icq1 * 32;
            #pragma unroll
            for (int mi = 0; mi < 4; ++mi)
                anx[mi] = *(const short8*)(aLane + (size_t)mi * 16 * KW + koff);
        }

        // ---- MFMA: 4x7 tiles per wave, tap shift via doff ----
        const int doff = (r / 3 - 1) * XCOLS + (r - (r / 3) * 3 - 1);
        short8 bfr[7];
        #pragma unroll
        for (int ni = 0; ni < 7; ++ni) {
            int lp   = lp0[ni] + doff;
            int slot = q ^ ((lp >> 1) & 3);
            bfr[ni]  = *(const short8*)&Xs[lp * 32 + slot * 8];
        }
        #pragma unroll
        for (int mi = 0; mi < 4; ++mi)
            #pragma unroll
            for (int ni = 0; ni < 7; ++ni)
                acc[mi][ni] = __builtin_amdgcn_mfma_f32_16x16x32_bf16(
                    afr[mi], bfr[ni], acc[mi][ni], 0, 0, 0);
    }

    // ---- epilogue: C/D layout col=lane&15, row=(lane>>4)*4+v (m89-verified) ----
    const int rowg = (lane >> 4) * 4;
    #pragma unroll
    for (int mi = 0; mi < 4; ++mi) {
        #pragma unroll
        for (int v = 0; v < 4; ++v) {
            const int oc = oc0 + wm + mi * 16 + rowg + v;
            const float bv = bias[oc];
            float* obase = out + (size_t)(b * OUT_C + oc) * HW;
            #pragma unroll
            for (int ni = 0; ni < 7; ++ni)
                obase[outoff[ni]] = acc[mi][ni][v] + bv;
        }
    }
}

extern "C" void kernel_launch(void* const* d_in, const int* in_sizes, int n_in,
                              void* d_out, int out_size, void* d_ws, size_t ws_size,
                              hipStream_t stream) {
    const float* x    = (const float*)d_in[0];
    const float* Wk   = (const float*)d_in[1];
    const float* bias = (const float*)d_in[2];
    float* out        = (float*)d_out;
    unsigned short* Wt = (unsigned short*)d_ws;   // 256*1152*2 = 589,824 B

    repack_w<<<dim3((OUT_C * KW + 255) / 256), dim3(256), 0, stream>>>(Wk, Wt);
    conv_gemm<<<dim3(BIMG * (HIMG / TH), OUT_C / BM), dim3(256), 0, stream>>>(x, Wt, bias, out);
}

// Round 4
// 220.213 us; speedup vs baseline: 1.0413x; 1.0413x over previous
//
#include <hip/hip_runtime.h>
#include <hip/hip_bf16.h>

#define IN_C  128
#define OUT_C 256
#define HIMG  56
#define WIMG  56
#define BIMG  32
#define HW    (HIMG * WIMG)     // 3136
#define KW    1152              // 9 * 128, GEMM K

#define BM    128               // oc per block
#define TH    4                 // output rows per block
#define XROWS 6                 // TH + 2 halo
#define XCOLS 58                // 56 + 2 halo
#define NPIXT (XROWS * XCOLS)   // 348 staged pixels
#define NFRAG (36 * 16)         // Wt2 fragments: 36 k-tiles x 16 oc-groups

typedef __attribute__((ext_vector_type(8))) short short8;
typedef __attribute__((ext_vector_type(4))) float float4_;

__device__ __forceinline__ unsigned short f32_to_bf16_rne(float f) {
    unsigned u = __builtin_bit_cast(unsigned, f);
    u += 0x7FFFu + ((u >> 16) & 1u);
    return (unsigned short)(u >> 16);
}

// Wt2: weights in EXACT MFMA A-fragment order. Fragment fg = t*16 + g holds
// oc rows g*16..+16, k-slice t (tap r=t%9, channels (t/9)*32..+32).
// Element (lane, jj): oc = g*16 + (lane&15), ic = icq*32 + (lane>>4)*8 + jj.
// One wave's A-frag load = contiguous 1024 B -> perfectly coalesced.
__global__ void prep_w2(const float* __restrict__ Wk, unsigned short* __restrict__ Wt2) {
    int idx = blockIdx.x * 256 + threadIdx.x;     // (t*16+g)*64 + lane
    if (idx >= NFRAG * 64) return;
    int lane = idx & 63;
    int fg   = idx >> 6;
    int g    = fg & 15, t = fg >> 4;
    int icq  = t / 9, r = t - icq * 9;
    int oc   = g * 16 + (lane & 15);
    int icb  = icq * 32 + (lane >> 4) * 8;
    short8 v;
    #pragma unroll
    for (int jj = 0; jj < 8; ++jj)
        v[jj] = (short)f32_to_bf16_rne(Wk[(size_t)oc * KW + (icb + jj) * 9 + r]);
    *(short8*)(Wt2 + (size_t)idx * 8) = v;
}

// x NCHW fp32 -> xp[b][hw][c] bf16 (pixel-major, 128 ch contiguous = 256 B)
__global__ void prep_x(const float* __restrict__ x, unsigned short* __restrict__ xp) {
    int idx = blockIdx.x * 256 + threadIdx.x;     // pix*16 + c8
    int c8  = idx & 15;
    int pix = idx >> 4;                           // b*HW + hw
    int b   = pix / HW;
    int hw  = pix - b * HW;
    const float* src = x + (size_t)(b * IN_C + c8 * 8) * HW + hw;
    short8 v;
    #pragma unroll
    for (int j = 0; j < 8; ++j)
        v[j] = (short)f32_to_bf16_rne(src[(size_t)j * HW]);
    *(short8*)(xp + (size_t)pix * IN_C + c8 * 8) = v;
}

// Implicit-GEMM conv. A frags stream from fragment-ordered Wt2 (coalesced,
// 1-t prefetch, no LDS, no per-t barriers). Xs staged once per icq (8
// barriers total). B-frag n-mapping = 8 cols x 2 rows so the 7 ds_read_b128
// share one base address with immediate offsets (ni*512 B), swizzle-phase
// invariant across ni.
template<bool XP>
__global__ __launch_bounds__(256, 2) void conv_gemm(
    const float* __restrict__ x, const unsigned short* __restrict__ xp,
    const unsigned short* __restrict__ Wt2,
    const float* __restrict__ bias, float* __restrict__ out)
{
    __shared__ short Xs[NPIXT * 32];      // 22272 B

    const int tid  = threadIdx.x;
    const int lane = tid & 63;
    const int wid  = tid >> 6;
    const int bx   = blockIdx.x;          // 0..447
    const int b    = bx / 14;
    const int h0   = (bx - b * 14) * TH;
    const int oc0  = blockIdx.y * BM;

    const int wm   = (wid >> 1) * 64;     // wave m-quadrant
    const int wrow = (wid & 1) * 2;       // wave n-quadrant = row pair {0,1}|{2,3}
    const int j    = lane & 15;
    const int q    = lane >> 4;

    // B n-mapping: fragment ni, col j -> pixel (h = wrow + (j>>3), w = ni*8 + (j&7))
    const int hloc = wrow + (j >> 3);
    const int lp00 = (hloc + 1) * XCOLS + (j & 7) + 1;   // tap(0,0) pixel, ni=0
    const int out0 = (h0 + hloc) * WIMG + (j & 7);

    // A: fragment group base g0 = (oc0+wm)/16; lane-contiguous fragments
    const unsigned short* aPtr =
        Wt2 + ((size_t)((oc0 >> 4) + (wm >> 4)) * 64 + lane) * 8;

    float4_ acc[4][7];
    #pragma unroll
    for (int mi = 0; mi < 4; ++mi)
        #pragma unroll
        for (int ni = 0; ni < 7; ++ni) acc[mi][ni] = (float4_)0.0f;

    short8 anx[4];
    #pragma unroll
    for (int mi = 0; mi < 4; ++mi)
        anx[mi] = *(const short8*)(aPtr + mi * 512);

    for (int t = 0; t < 36; ++t) {        // t = icq*9 + r
        const int icq = t / 9;
        const int r   = t - icq * 9;

        if (r == 0) {
            if (t) __syncthreads();       // all waves done reading prev Xs
            if (XP) {
                const unsigned short* xpb =
                    xp + (size_t)b * HW * IN_C + icq * 32;
                for (int c = tid; c < NPIXT * 4; c += 256) {
                    int p = c >> 2, qb = c & 3;
                    int row  = p / XCOLS;
                    int colw = p - row * XCOLS;
                    int h = h0 + row - 1, w = colw - 1;
                    bool valid = ((unsigned)h < HIMG) & ((unsigned)w < WIMG);
                    short8 v = (short8)0;
                    if (valid)
                        v = *(const short8*)(xpb + (size_t)(h * WIMG + w) * IN_C + qb * 8);
                    int sw = (p >> 1) & 3;
                    *(short8*)&Xs[p * 32 + ((qb ^ sw) * 8)] = v;
                }
            } else {
                for (int p = tid; p < NPIXT; p += 256) {
                    int row  = p / XCOLS;
                    int colw = p - row * XCOLS;
                    int h = h0 + row - 1, w = colw - 1;
                    bool valid = ((unsigned)h < HIMG) & ((unsigned)w < WIMG);
                    int sw = (p >> 1) & 3;
                    #pragma unroll
                    for (int qb = 0; qb < 4; ++qb) {
                        const float* src = x + (size_t)(b * IN_C + icq * 32 + qb * 8) * HW
                                             + (ptrdiff_t)(h * WIMG + w);
                        short8 v;
                        #pragma unroll
                        for (int jj = 0; jj < 8; ++jj) {
                            float f = valid ? src[(size_t)jj * HW] : 0.0f;
                            v[jj] = (short)f32_to_bf16_rne(f);
                        }
                        *(short8*)&Xs[p * 32 + ((qb ^ sw) * 8)] = v;
                    }
                }
            }
            __syncthreads();
        }

        // consume prefetched A; issue next prefetch (coalesced 1024B bursts)
        short8 afr[4];
        #pragma unroll
        for (int mi = 0; mi < 4; ++mi) afr[mi] = anx[mi];
        if (t < 35) {
            const unsigned short* aNxt = aPtr + (size_t)(t + 1) * 16 * 512;
            #pragma unroll
            for (int mi = 0; mi < 4; ++mi)
                anx[mi] = *(const short8*)(aNxt + mi * 512);
        }

        // B frags: one base, 7 immediate-offset ds_read_b128
        const int doff = (r / 3 - 1) * XCOLS + (r - (r / 3) * 3 - 1);
        const int lpb  = lp00 + doff;
        const int slot = q ^ ((lpb >> 1) & 3);
        const short* bbase = &Xs[lpb * 32 + slot * 8];
        short8 bfr[7];
        #pragma unroll
        for (int ni = 0; ni < 7; ++ni)
            bfr[ni] = *(const short8*)(bbase + ni * 256);

        #pragma unroll
        for (int mi = 0; mi < 4; ++mi)
            #pragma unroll
            for (int ni = 0; ni < 7; ++ni)
                acc[mi][ni] = __builtin_amdgcn_mfma_f32_16x16x32_bf16(
                    afr[mi], bfr[ni], acc[mi][ni], 0, 0, 0);
    }

    // epilogue: C/D layout col=lane&15, row=(lane>>4)*4+v (m89-verified)
    const int rowg = (lane >> 4) * 4;
    #pragma unroll
    for (int mi = 0; mi < 4; ++mi) {
        #pragma unroll
        for (int v = 0; v < 4; ++v) {
            const int oc = oc0 + wm + mi * 16 + rowg + v;
            const float bv = bias[oc];
            float* obase = out + (size_t)(b * OUT_C + oc) * HW + out0;
            #pragma unroll
            for (int ni = 0; ni < 7; ++ni)
                obase[ni * 8] = acc[mi][ni][v] + bv;
        }
    }
}

extern "C" void kernel_launch(void* const* d_in, const int* in_sizes, int n_in,
                              void* d_out, int out_size, void* d_ws, size_t ws_size,
                              hipStream_t stream) {
    const float* x    = (const float*)d_in[0];
    const float* Wk   = (const float*)d_in[1];
    const float* bias = (const float*)d_in[2];
    float* out        = (float*)d_out;

    unsigned short* Wt2 = (unsigned short*)d_ws;            // 589,824 B
    const size_t xp_off   = (size_t)NFRAG * 64 * 8 * 2;     // 589,824
    const size_t xp_bytes = (size_t)BIMG * HW * IN_C * 2;   // 25,690,112
    unsigned short* xp = (unsigned short*)((char*)d_ws + xp_off);
    const bool use_xp = ws_size >= xp_off + xp_bytes;

    prep_w2<<<dim3((NFRAG * 64 + 255) / 256), dim3(256), 0, stream>>>(Wk, Wt2);
    if (use_xp) {
        prep_x<<<dim3(BIMG * HW * 16 / 256), dim3(256), 0, stream>>>(x, xp);
        conv_gemm<true><<<dim3(BIMG * (HIMG / TH), OUT_C / BM), dim3(256), 0, stream>>>(
            x, xp, Wt2, bias, out);
    } else {
        conv_gemm<false><<<dim3(BIMG * (HIMG / TH), OUT_C / BM), dim3(256), 0, stream>>>(
            x, xp, Wt2, bias, out);
    }
}